// Round 1
// baseline (2150.434 us; speedup 1.0000x reference)
//
#include <hip/hip_runtime.h>
#include <hip/hip_bf16.h>

// Problem constants
#define BTOT 8192
#define TSTEPS 50
#define FIN 25
#define H1C 200
#define G1C 800     // 4*H1
#define H2C 100
#define KPAD 256    // K = 200(h) + 25(x) padded to 256
#define BM 32       // batch rows per block
#define AST 264     // As row stride in bf16 elems (528 B: dword-stride 132 == 4 mod 32 -> phase-conflict-free b128 reads)
#define HFST 210    // hf row stride in bf16 (420 B -> 105 dw == 9 mod 32, coprime -> conflict-free column reads)

typedef __bf16 bf16_t;
typedef __bf16 bf16x8 __attribute__((ext_vector_type(8)));
typedef float f32x16 __attribute__((ext_vector_type(16)));

__device__ __forceinline__ float sigm(float x) {
  float e = __builtin_amdgcn_exp2f(-1.4426950408889634f * x);
  return __builtin_amdgcn_rcpf(1.0f + e);
}
__device__ __forceinline__ float tanha(float x) {
  float e = __builtin_amdgcn_exp2f(-2.885390081777927f * x);
  return 2.0f * __builtin_amdgcn_rcpf(1.0f + e) - 1.0f;
}

// Column permutation: col c (0..799): tile nt=c>>5, local=c&31,
// unit u = nt*8 + (local>>2), gate g = local&3 (PyTorch order i,f,g,o),
// original row = g*200 + u. K layout: [W_hh1(200) | W_ih1(25) | zeros(31)]
__global__ void prep_kernel(const float* __restrict__ Wih1, const float* __restrict__ Whh1,
                            const float* __restrict__ bih1, const float* __restrict__ bhh1,
                            bf16_t* __restrict__ Wcat, float* __restrict__ bcat) {
  int tid = blockIdx.x * blockDim.x + threadIdx.x;
  for (int e = tid; e < G1C * KPAD; e += gridDim.x * blockDim.x) {
    int n = e >> 8, k = e & 255;
    int nt = n >> 5, local = n & 31;
    int u = nt * 8 + (local >> 2);
    int gate = local & 3;
    int orig = gate * 200 + u;
    float v = 0.f;
    if (k < 200) v = Whh1[orig * 200 + k];
    else if (k < 225) v = Wih1[orig * 25 + (k - 200)];
    Wcat[e] = (bf16_t)v;
  }
  if (tid < G1C) {
    int n = tid;
    int nt = n >> 5, local = n & 31;
    int u = nt * 8 + (local >> 2);
    int gate = local & 3;
    int orig = gate * 200 + u;
    bcat[n] = bih1[orig] + bhh1[orig];
  }
}

__global__ __launch_bounds__(256, 1) void lstm_main(
    const float* __restrict__ x,
    const bf16_t* __restrict__ Wcat, const float* __restrict__ bcat,
    const float* __restrict__ h10, const float* __restrict__ c10,
    const float* __restrict__ Wih2, const float* __restrict__ Whh2,
    const float* __restrict__ bih2, const float* __restrict__ bhh2,
    const float* __restrict__ fcw, const float* __restrict__ fcb,
    const float* __restrict__ h20, const float* __restrict__ c20,
    float* __restrict__ out) {

  __shared__ __align__(16) bf16_t As[BM * AST];   // [row][k] A-operand: h(0..199) | x_t(200..224) | zeros
  __shared__ bf16_t hfs[BM * HFST];               // final h1 (for fused layer-2)
  __shared__ float h2s[BM * 101];
  __shared__ float c2s[BM * 101];
  __shared__ float facc[BM];

  const int tid = threadIdx.x;
  const int lane = tid & 63;
  const int wid = tid >> 6;               // 0..3
  const int gbase = blockIdx.x * BM;

  // wave tile assignment over 25 N-tiles: 7/6/6/6
  const int tstart = (wid == 0) ? 0 : (1 + wid * 6);
  const int tcnt = (wid == 0) ? 7 : 6;

  const int l31 = lane & 31;
  const int h5 = lane >> 5;               // k-chunk of A/B fragment
  const int p = lane & 3;                 // gate owned by this lane (quad position)
  const int uq = l31 >> 2;                // unit-in-tile 0..7

  // ---- prologue: zero A, stage h0 + x0, init biases and c ----
  for (int i = tid; i < BM * AST; i += 256) As[i] = (bf16_t)0.f;
  __syncthreads();
  for (int i = tid; i < BM * H1C; i += 256) {
    int r = i / H1C, u = i - r * H1C;
    As[r * AST + u] = (bf16_t)h10[(gbase + r) * H1C + u];
  }
  for (int i = tid; i < BM * FIN; i += 256) {
    int r = i / FIN, f = i - r * FIN;
    As[r * AST + 200 + f] = (bf16_t)x[(size_t)(gbase + r) * (TSTEPS * FIN) + f];
  }

  float bv[7];
  float cc[28];
  #pragma unroll
  for (int nt = 0; nt < 7; ++nt) {
    bv[nt] = 0.f;
    #pragma unroll
    for (int i = 0; i < 4; ++i) cc[nt * 4 + i] = 0.f;
    if (nt < tcnt) {
      bv[nt] = bcat[(tstart + nt) * 32 + l31];
      int u = (tstart + nt) * 8 + uq;
      #pragma unroll
      for (int i = 0; i < 4; ++i) {
        int r = 8 * p + 4 * h5 + i;
        cc[nt * 4 + i] = c10[(gbase + r) * H1C + u];
      }
    }
  }

  // x prefetch slots (800 elems over 256 threads)
  size_t xoff[4]; int xrw[4], xcf[4]; bool xv[4];
  #pragma unroll
  for (int j = 0; j < 4; ++j) {
    int i = tid + 256 * j;
    xv[j] = (i < BM * FIN);
    int r = i / FIN; if (r > BM - 1) r = BM - 1;
    int f = i - (i / FIN) * FIN;
    xrw[j] = r; xcf[j] = f;
    xoff[j] = (size_t)(gbase + r) * (TSTEPS * FIN) + f;
  }
  __syncthreads();

  const bf16x8* __restrict__ Wv = (const bf16x8*)Wcat;   // row stride = 32 units

  float hst[28];

  // ---- recurrence ----
  #pragma unroll 1
  for (int t = 0; t < TSTEPS; ++t) {
    // prefetch x_{t+1} early (hides HBM latency under the MFMA/load stream)
    float xr[4] = {0.f, 0.f, 0.f, 0.f};
    if (t < TSTEPS - 1) {
      #pragma unroll
      for (int j = 0; j < 4; ++j) if (xv[j]) xr[j] = x[xoff[j] + (size_t)(t + 1) * FIN];
    }

    // double-buffered B prefetch; per-tile: 16 loads -> 16 MFMA -> cell-update VALU
    bf16x8 b0[16], b1[16];
    {
      const bf16x8* wp = Wv + ((tstart * 32 + l31) * 32 + h5);
      #pragma unroll
      for (int kt = 0; kt < 16; ++kt) b0[kt] = wp[kt * 2];
    }

    #pragma unroll
    for (int nt = 0; nt < 7; ++nt) {
      if (nt < tcnt) {
        if (nt + 1 < tcnt) {
          const bf16x8* wp = Wv + (((tstart + nt + 1) * 32 + l31) * 32 + h5);
          if (nt & 1) {
            #pragma unroll
            for (int kt = 0; kt < 16; ++kt) b0[kt] = wp[kt * 2];
          } else {
            #pragma unroll
            for (int kt = 0; kt < 16; ++kt) b1[kt] = wp[kt * 2];
          }
        }
        f32x16 A;
        #pragma unroll
        for (int q = 0; q < 16; ++q) A[q] = bv[nt];
        #pragma unroll
        for (int kt = 0; kt < 16; ++kt) {
          bf16x8 a = *(const bf16x8*)(&As[l31 * AST + kt * 16 + h5 * 8]);
          bf16x8 b = (nt & 1) ? b1[kt] : b0[kt];
          A = __builtin_amdgcn_mfma_f32_32x32x16_bf16(a, b, A, 0, 0, 0);
        }
        // cell update: gather 4 gates of this lane's 4 rows via quad shfl_xor
        #pragma unroll
        for (int i = 0; i < 4; ++i) {
          float s0 = A[i], s1 = A[4 + i], s2 = A[8 + i], s3 = A[12 + i];
          float own = (p == 0) ? s0 : (p == 1) ? s1 : (p == 2) ? s2 : s3;
          int q1 = p ^ 1;
          float t1 = (q1 == 0) ? s0 : (q1 == 1) ? s1 : (q1 == 2) ? s2 : s3;
          float r1 = __shfl_xor(t1, 1);
          int q2 = p ^ 2;
          float t2 = (q2 == 0) ? s0 : (q2 == 1) ? s1 : (q2 == 2) ? s2 : s3;
          float r2 = __shfl_xor(t2, 2);
          int q3 = p ^ 3;
          float t3 = (q3 == 0) ? s0 : (q3 == 1) ? s1 : (q3 == 2) ? s2 : s3;
          float r3 = __shfl_xor(t3, 3);
          float vi = (p == 0) ? own : (p == 1) ? r1 : (p == 2) ? r2 : r3;
          float vf = (p == 0) ? r1 : (p == 1) ? own : (p == 2) ? r3 : r2;
          float vg = (p == 0) ? r2 : (p == 1) ? r3 : (p == 2) ? own : r1;
          float vo = (p == 0) ? r3 : (p == 1) ? r2 : (p == 2) ? r1 : own;
          float ig = sigm(vi), fg = sigm(vf), gg = tanha(vg), og = sigm(vo);
          float cn = fg * cc[nt * 4 + i] + ig * gg;
          cc[nt * 4 + i] = cn;
          hst[nt * 4 + i] = og * tanha(cn);
        }
      }
    }

    __syncthreads();   // all A-reads done
    // publish h_{t+1} (bf16) and x_{t+1}
    #pragma unroll
    for (int nt = 0; nt < 7; ++nt) {
      if (nt < tcnt) {
        int u = (tstart + nt) * 8 + uq;
        #pragma unroll
        for (int i = 0; i < 4; ++i) {
          int r = 8 * p + 4 * h5 + i;
          As[r * AST + u] = (bf16_t)hst[nt * 4 + i];
          if (t == TSTEPS - 1) hfs[r * HFST + u] = (bf16_t)hst[nt * 4 + i];
        }
      }
    }
    if (t < TSTEPS - 1) {
      #pragma unroll
      for (int j = 0; j < 4; ++j) if (xv[j]) As[xrw[j] * AST + 200 + xcf[j]] = (bf16_t)xr[j];
    }
    __syncthreads();
  }

  // ---- fused layer-2 (single LSTM cell on final h1) + FC + sigmoid ----
  for (int i = tid; i < BM * H2C; i += 256) {
    int r = i / H2C, u = i - r * H2C;
    h2s[r * 101 + u] = h20[(gbase + r) * H2C + u];
    c2s[r * 101 + u] = c20[(gbase + r) * H2C + u];
  }
  if (tid < BM) facc[tid] = 0.f;
  __syncthreads();

  const float fcb0 = fcb[0];
  for (int i = tid; i < BM * H2C; i += 256) {
    int u = i >> 5;       // 0..99  (consecutive threads share u -> W rows broadcast)
    int r = i & 31;
    float a0 = bih2[u] + bhh2[u];
    float a1 = bih2[100 + u] + bhh2[100 + u];
    float a2 = bih2[200 + u] + bhh2[200 + u];
    float a3 = bih2[300 + u] + bhh2[300 + u];
    const float4* w0 = (const float4*)(Wih2 + (0 * H2C + u) * H1C);
    const float4* w1 = (const float4*)(Wih2 + (1 * H2C + u) * H1C);
    const float4* w2 = (const float4*)(Wih2 + (2 * H2C + u) * H1C);
    const float4* w3 = (const float4*)(Wih2 + (3 * H2C + u) * H1C);
    #pragma unroll 5
    for (int k4 = 0; k4 < 50; ++k4) {
      float hk0 = (float)hfs[r * HFST + 4 * k4 + 0];
      float hk1 = (float)hfs[r * HFST + 4 * k4 + 1];
      float hk2 = (float)hfs[r * HFST + 4 * k4 + 2];
      float hk3 = (float)hfs[r * HFST + 4 * k4 + 3];
      float4 wv;
      wv = w0[k4]; a0 += hk0 * wv.x + hk1 * wv.y + hk2 * wv.z + hk3 * wv.w;
      wv = w1[k4]; a1 += hk0 * wv.x + hk1 * wv.y + hk2 * wv.z + hk3 * wv.w;
      wv = w2[k4]; a2 += hk0 * wv.x + hk1 * wv.y + hk2 * wv.z + hk3 * wv.w;
      wv = w3[k4]; a3 += hk0 * wv.x + hk1 * wv.y + hk2 * wv.z + hk3 * wv.w;
    }
    const float4* v0 = (const float4*)(Whh2 + (0 * H2C + u) * H2C);
    const float4* v1 = (const float4*)(Whh2 + (1 * H2C + u) * H2C);
    const float4* v2 = (const float4*)(Whh2 + (2 * H2C + u) * H2C);
    const float4* v3 = (const float4*)(Whh2 + (3 * H2C + u) * H2C);
    #pragma unroll 5
    for (int k4 = 0; k4 < 25; ++k4) {
      float hk0 = h2s[r * 101 + 4 * k4 + 0];
      float hk1 = h2s[r * 101 + 4 * k4 + 1];
      float hk2 = h2s[r * 101 + 4 * k4 + 2];
      float hk3 = h2s[r * 101 + 4 * k4 + 3];
      float4 wv;
      wv = v0[k4]; a0 += hk0 * wv.x + hk1 * wv.y + hk2 * wv.z + hk3 * wv.w;
      wv = v1[k4]; a1 += hk0 * wv.x + hk1 * wv.y + hk2 * wv.z + hk3 * wv.w;
      wv = v2[k4]; a2 += hk0 * wv.x + hk1 * wv.y + hk2 * wv.z + hk3 * wv.w;
      wv = v3[k4]; a3 += hk0 * wv.x + hk1 * wv.y + hk2 * wv.z + hk3 * wv.w;
    }
    float ig = sigm(a0), fg = sigm(a1), gg = tanha(a2), og = sigm(a3);
    float cn = fg * c2s[r * 101 + u] + ig * gg;
    float h2v = og * tanha(cn);
    atomicAdd(&facc[r], h2v * fcw[u]);
  }
  __syncthreads();
  if (tid < BM) out[gbase + tid] = sigm(facc[tid] + fcb0);
}

extern "C" void kernel_launch(void* const* d_in, const int* in_sizes, int n_in,
                              void* d_out, int out_size, void* d_ws, size_t ws_size,
                              hipStream_t stream) {
  const float* x    = (const float*)d_in[0];
  const float* Wih1 = (const float*)d_in[1];
  const float* Whh1 = (const float*)d_in[2];
  const float* bih1 = (const float*)d_in[3];
  const float* bhh1 = (const float*)d_in[4];
  const float* Wih2 = (const float*)d_in[5];
  const float* Whh2 = (const float*)d_in[6];
  const float* bih2 = (const float*)d_in[7];
  const float* bhh2 = (const float*)d_in[8];
  const float* fcw  = (const float*)d_in[9];
  const float* fcb  = (const float*)d_in[10];
  const float* h10  = (const float*)d_in[11];
  const float* c10  = (const float*)d_in[12];
  const float* h20  = (const float*)d_in[13];
  const float* c20  = (const float*)d_in[14];
  float* out = (float*)d_out;

  bf16_t* Wcat = (bf16_t*)d_ws;
  float* bcat = (float*)((char*)d_ws + (size_t)G1C * KPAD * sizeof(bf16_t));

  prep_kernel<<<256, 256, 0, stream>>>(Wih1, Whh1, bih1, bhh1, Wcat, bcat);
  lstm_main<<<BTOT / BM, 256, 0, stream>>>(x, Wcat, bcat, h10, c10,
                                           Wih2, Whh2, bih2, bhh2,
                                           fcw, fcb, h20, c20, out);
}

// Round 2
// 1052.550 us; speedup vs baseline: 2.0431x; 2.0431x over previous
//
#include <hip/hip_runtime.h>
#include <hip/hip_bf16.h>

// Problem constants
#define BTOT 8192
#define TSTEPS 50
#define FIN 25
#define H1C 200
#define G1C 800     // 4*H1
#define H2C 100
#define KPAD 256    // K = 200(h) + 25(x) padded to 256
#define BM 32       // batch rows per block
#define AST 264     // As row stride in bf16 elems (528 B)

typedef __bf16 bf16_t;
typedef __bf16 bf16x8 __attribute__((ext_vector_type(8)));
typedef float f32x16 __attribute__((ext_vector_type(16)));

__device__ __forceinline__ float sigm(float x) {
  float e = __builtin_amdgcn_exp2f(-1.4426950408889634f * x);
  return __builtin_amdgcn_rcpf(1.0f + e);
}
__device__ __forceinline__ float tanha(float x) {
  float e = __builtin_amdgcn_exp2f(-2.885390081777927f * x);
  return 2.0f * __builtin_amdgcn_rcpf(1.0f + e) - 1.0f;
}

// Column permutation: col c (0..799): tile nt=c>>5, local=c&31,
// unit u = nt*8 + (local>>2), gate g = local&3 (PyTorch order i,f,g,o),
// original row = g*200 + u. K layout: [W_hh1(200) | W_ih1(25) | zeros(31)]
__global__ void prep_kernel(const float* __restrict__ Wih1, const float* __restrict__ Whh1,
                            const float* __restrict__ bih1, const float* __restrict__ bhh1,
                            bf16_t* __restrict__ Wcat, float* __restrict__ bcat) {
  int tid = blockIdx.x * blockDim.x + threadIdx.x;
  for (int e = tid; e < G1C * KPAD; e += gridDim.x * blockDim.x) {
    int n = e >> 8, k = e & 255;
    int nt = n >> 5, local = n & 31;
    int u = nt * 8 + (local >> 2);
    int gate = local & 3;
    int orig = gate * 200 + u;
    float v = 0.f;
    if (k < 200) v = Whh1[orig * 200 + k];
    else if (k < 225) v = Wih1[orig * 25 + (k - 200)];
    Wcat[e] = (bf16_t)v;
  }
  if (tid < G1C) {
    int n = tid;
    int nt = n >> 5, local = n & 31;
    int u = nt * 8 + (local >> 2);
    int gate = local & 3;
    int orig = gate * 200 + u;
    bcat[n] = bih1[orig] + bhh1[orig];
  }
}

__global__ __launch_bounds__(512, 2) void lstm_main(
    const float* __restrict__ x,
    const bf16_t* __restrict__ Wcat, const float* __restrict__ bcat,
    const float* __restrict__ h10, const float* __restrict__ c10,
    const float* __restrict__ Wih2, const float* __restrict__ Whh2,
    const float* __restrict__ bih2, const float* __restrict__ bhh2,
    const float* __restrict__ fcw, const float* __restrict__ fcb,
    const float* __restrict__ h20, const float* __restrict__ c20,
    float* __restrict__ out) {

  __shared__ __align__(16) bf16_t As[2][BM * AST];  // double-buffered A: h(0..199)|x(200..224)|0
  __shared__ float h2s[BM * 101];
  __shared__ float c2s[BM * 101];
  __shared__ float facc[BM];

  const int tid = threadIdx.x;
  const int lane = tid & 63;
  const int wid = tid >> 6;               // 0..7
  const int gbase = blockIdx.x * BM;

  // tile assignment over 25 N-tiles: wave0: 4, waves1-7: 3
  const int tstart = (wid == 0) ? 0 : (1 + 3 * wid);
  const int tcnt = (wid == 0) ? 4 : 3;

  const int l31 = lane & 31;
  const int h5 = lane >> 5;               // k-chunk of A/B fragment
  const int p = lane & 3;                 // gate owned by this lane (quad position)
  const int uq = l31 >> 2;                // unit-in-tile 0..7

  // ---- prologue: zero both A buffers, stage h0 + x0 ----
  for (int i = tid; i < 2 * BM * AST; i += 512) ((bf16_t*)As)[i] = (bf16_t)0.f;
  __syncthreads();
  for (int i = tid; i < BM * H1C; i += 512) {
    int r = i / H1C, u = i - r * H1C;
    As[0][r * AST + u] = (bf16_t)h10[(gbase + r) * H1C + u];
  }
  for (int i = tid; i < BM * FIN; i += 512) {
    int r = i / FIN, f = i - r * FIN;
    As[0][r * AST + 200 + f] = (bf16_t)x[(size_t)(gbase + r) * (TSTEPS * FIN) + f];
  }

  float bv[4];
  float cc[16];
  #pragma unroll
  for (int nt = 0; nt < 4; ++nt) {
    bv[nt] = 0.f;
    #pragma unroll
    for (int i = 0; i < 4; ++i) cc[nt * 4 + i] = 0.f;
    if (nt < tcnt) {
      bv[nt] = bcat[(tstart + nt) * 32 + l31];
      int u = (tstart + nt) * 8 + uq;
      #pragma unroll
      for (int i = 0; i < 4; ++i) {
        int r = 8 * p + 4 * h5 + i;
        cc[nt * 4 + i] = c10[(gbase + r) * H1C + u];
      }
    }
  }

  // x prefetch slots (800 elems over 512 threads -> 2 slots)
  unsigned xg[2], xl[2]; bool xv[2];
  #pragma unroll
  for (int j = 0; j < 2; ++j) {
    int i = tid + 512 * j;
    xv[j] = (i < BM * FIN);
    int r = i / FIN; if (r > BM - 1) r = BM - 1;
    int f = i - (i / FIN) * FIN;
    xg[j] = (unsigned)(gbase + r) * (TSTEPS * FIN) + f;
    xl[j] = (unsigned)(r * AST + 200 + f);
  }
  __syncthreads();

  const bf16x8* __restrict__ Wv = (const bf16x8*)Wcat;   // frag row stride = 32

  // B fragment double buffers (static-index only; selected by wave-uniform branch)
  bf16x8 bA[16], bB[16];
  int pb = 0;
  {
    const bf16x8* wp = Wv + ((tstart * 32 + l31) * 32 + h5);
    #pragma unroll
    for (int kt = 0; kt < 16; ++kt) bA[kt] = wp[kt * 2];
  }

  // ---- recurrence ----
  #pragma unroll 1
  for (int t = 0; t < TSTEPS; ++t) {
    const bf16_t* __restrict__ Ac = As[t & 1];
    bf16_t* __restrict__ An = As[(t & 1) ^ 1];

    // prefetch x_{t+1}
    float xr[2] = {0.f, 0.f};
    if (t < TSTEPS - 1) {
      #pragma unroll
      for (int j = 0; j < 2; ++j) if (xv[j]) xr[j] = x[xg[j] + (unsigned)(t + 1) * FIN];
    }

    #pragma unroll
    for (int nt = 0; nt < 4; ++nt) {
      if (nt < tcnt) {
        // prefetch target: next tile this step, else this wave's first tile (next step)
        int ptile = (nt + 1 < tcnt) ? (tstart + nt + 1) : tstart;
        const bf16x8* wp = Wv + ((ptile * 32 + l31) * 32 + h5);

        f32x16 A;
        #pragma unroll
        for (int q = 0; q < 16; ++q) A[q] = bv[nt];

        if (pb == 0) {
          #pragma unroll
          for (int kt = 0; kt < 16; ++kt) bB[kt] = wp[kt * 2];
          #pragma unroll
          for (int kt = 0; kt < 16; ++kt) {
            bf16x8 a = *(const bf16x8*)(&Ac[l31 * AST + kt * 16 + h5 * 8]);
            A = __builtin_amdgcn_mfma_f32_32x32x16_bf16(a, bA[kt], A, 0, 0, 0);
          }
        } else {
          #pragma unroll
          for (int kt = 0; kt < 16; ++kt) bA[kt] = wp[kt * 2];
          #pragma unroll
          for (int kt = 0; kt < 16; ++kt) {
            bf16x8 a = *(const bf16x8*)(&Ac[l31 * AST + kt * 16 + h5 * 8]);
            A = __builtin_amdgcn_mfma_f32_32x32x16_bf16(a, bB[kt], A, 0, 0, 0);
          }
        }
        pb ^= 1;

        // cell update: gather 4 gates of this lane's 4 rows via quad shfl_xor
        int u = (tstart + nt) * 8 + uq;
        #pragma unroll
        for (int i = 0; i < 4; ++i) {
          float s0 = A[i], s1 = A[4 + i], s2 = A[8 + i], s3 = A[12 + i];
          float own = (p == 0) ? s0 : (p == 1) ? s1 : (p == 2) ? s2 : s3;
          int q1 = p ^ 1;
          float t1 = (q1 == 0) ? s0 : (q1 == 1) ? s1 : (q1 == 2) ? s2 : s3;
          float r1 = __shfl_xor(t1, 1);
          int q2 = p ^ 2;
          float t2 = (q2 == 0) ? s0 : (q2 == 1) ? s1 : (q2 == 2) ? s2 : s3;
          float r2 = __shfl_xor(t2, 2);
          int q3 = p ^ 3;
          float t3 = (q3 == 0) ? s0 : (q3 == 1) ? s1 : (q3 == 2) ? s2 : s3;
          float r3 = __shfl_xor(t3, 3);
          float vi = (p == 0) ? own : (p == 1) ? r1 : (p == 2) ? r2 : r3;
          float vf = (p == 0) ? r1 : (p == 1) ? own : (p == 2) ? r3 : r2;
          float vg = (p == 0) ? r2 : (p == 1) ? r3 : (p == 2) ? own : r1;
          float vo = (p == 0) ? r3 : (p == 1) ? r2 : (p == 2) ? r1 : own;
          float ig = sigm(vi), fg = sigm(vf), gg = tanha(vg), og = sigm(vo);
          float cn = fg * cc[nt * 4 + i] + ig * gg;
          cc[nt * 4 + i] = cn;
          float hv = og * tanha(cn);
          int r = 8 * p + 4 * h5 + i;
          An[r * AST + u] = (bf16_t)hv;    // publish h_{t+1} into the other buffer
        }
      }
    }

    if (t < TSTEPS - 1) {
      #pragma unroll
      for (int j = 0; j < 2; ++j) if (xv[j]) An[xl[j]] = (bf16_t)xr[j];
    }
    __syncthreads();   // next-step buffer fully published
  }

  // final h1 lives in As[0] (TSTEPS even), cols 0..199, stride AST
  const bf16_t* __restrict__ hf = As[0];

  // ---- fused layer-2 (single LSTM cell on final h1) + FC + sigmoid ----
  for (int i = tid; i < BM * H2C; i += 512) {
    int r = i / H2C, u = i - r * H2C;
    h2s[r * 101 + u] = h20[(gbase + r) * H2C + u];
    c2s[r * 101 + u] = c20[(gbase + r) * H2C + u];
  }
  if (tid < BM) facc[tid] = 0.f;
  __syncthreads();

  const float fcb0 = fcb[0];
  for (int i = tid; i < BM * H2C; i += 512) {
    int u = i >> 5;       // 0..99 (consecutive threads share u -> W rows broadcast)
    int r = i & 31;
    float a0 = bih2[u] + bhh2[u];
    float a1 = bih2[100 + u] + bhh2[100 + u];
    float a2 = bih2[200 + u] + bhh2[200 + u];
    float a3 = bih2[300 + u] + bhh2[300 + u];
    const float4* w0 = (const float4*)(Wih2 + (0 * H2C + u) * H1C);
    const float4* w1 = (const float4*)(Wih2 + (1 * H2C + u) * H1C);
    const float4* w2 = (const float4*)(Wih2 + (2 * H2C + u) * H1C);
    const float4* w3 = (const float4*)(Wih2 + (3 * H2C + u) * H1C);
    #pragma unroll 5
    for (int k4 = 0; k4 < 50; ++k4) {
      float hk0 = (float)hf[r * AST + 4 * k4 + 0];
      float hk1 = (float)hf[r * AST + 4 * k4 + 1];
      float hk2 = (float)hf[r * AST + 4 * k4 + 2];
      float hk3 = (float)hf[r * AST + 4 * k4 + 3];
      float4 wv;
      wv = w0[k4]; a0 += hk0 * wv.x + hk1 * wv.y + hk2 * wv.z + hk3 * wv.w;
      wv = w1[k4]; a1 += hk0 * wv.x + hk1 * wv.y + hk2 * wv.z + hk3 * wv.w;
      wv = w2[k4]; a2 += hk0 * wv.x + hk1 * wv.y + hk2 * wv.z + hk3 * wv.w;
      wv = w3[k4]; a3 += hk0 * wv.x + hk1 * wv.y + hk2 * wv.z + hk3 * wv.w;
    }
    const float4* v0 = (const float4*)(Whh2 + (0 * H2C + u) * H2C);
    const float4* v1 = (const float4*)(Whh2 + (1 * H2C + u) * H2C);
    const float4* v2 = (const float4*)(Whh2 + (2 * H2C + u) * H2C);
    const float4* v3 = (const float4*)(Whh2 + (3 * H2C + u) * H2C);
    #pragma unroll 5
    for (int k4 = 0; k4 < 25; ++k4) {
      float hk0 = h2s[r * 101 + 4 * k4 + 0];
      float hk1 = h2s[r * 101 + 4 * k4 + 1];
      float hk2 = h2s[r * 101 + 4 * k4 + 2];
      float hk3 = h2s[r * 101 + 4 * k4 + 3];
      float4 wv;
      wv = v0[k4]; a0 += hk0 * wv.x + hk1 * wv.y + hk2 * wv.z + hk3 * wv.w;
      wv = v1[k4]; a1 += hk0 * wv.x + hk1 * wv.y + hk2 * wv.z + hk3 * wv.w;
      wv = v2[k4]; a2 += hk0 * wv.x + hk1 * wv.y + hk2 * wv.z + hk3 * wv.w;
      wv = v3[k4]; a3 += hk0 * wv.x + hk1 * wv.y + hk2 * wv.z + hk3 * wv.w;
    }
    float ig = sigm(a0), fg = sigm(a1), gg = tanha(a2), og = sigm(a3);
    float cn = fg * c2s[r * 101 + u] + ig * gg;
    float h2v = og * tanha(cn);
    atomicAdd(&facc[r], h2v * fcw[u]);
  }
  __syncthreads();
  if (tid < BM) out[gbase + tid] = sigm(facc[tid] + fcb0);
}

extern "C" void kernel_launch(void* const* d_in, const int* in_sizes, int n_in,
                              void* d_out, int out_size, void* d_ws, size_t ws_size,
                              hipStream_t stream) {
  const float* x    = (const float*)d_in[0];
  const float* Wih1 = (const float*)d_in[1];
  const float* Whh1 = (const float*)d_in[2];
  const float* bih1 = (const float*)d_in[3];
  const float* bhh1 = (const float*)d_in[4];
  const float* Wih2 = (const float*)d_in[5];
  const float* Whh2 = (const float*)d_in[6];
  const float* bih2 = (const float*)d_in[7];
  const float* bhh2 = (const float*)d_in[8];
  const float* fcw  = (const float*)d_in[9];
  const float* fcb  = (const float*)d_in[10];
  const float* h10  = (const float*)d_in[11];
  const float* c10  = (const float*)d_in[12];
  const float* h20  = (const float*)d_in[13];
  const float* c20  = (const float*)d_in[14];
  float* out = (float*)d_out;

  bf16_t* Wcat = (bf16_t*)d_ws;
  float* bcat = (float*)((char*)d_ws + (size_t)G1C * KPAD * sizeof(bf16_t));

  prep_kernel<<<256, 256, 0, stream>>>(Wih1, Whh1, bih1, bhh1, Wcat, bcat);
  lstm_main<<<BTOT / BM, 512, 0, stream>>>(x, Wcat, bcat, h10, c10,
                                           Wih2, Whh2, bih2, bhh2,
                                           fcw, fcb, h20, c20, out);
}